// Round 20
// baseline (289.624 us; speedup 1.0000x reference)
//
#include <hip/hip_runtime.h>
#include <hip/hip_bf16.h>

#define FEATN 256
#define XROW  2048      // L*FEAT
#define MT    64        // rows per workgroup
#define LDST  264       // padded LDS row stride (bf16 elems)
#define TILE  (MT * LDST)
#define NSTEP 7

using f32x4 = __attribute__((ext_vector_type(4))) float;
using s16x8 = __attribute__((ext_vector_type(8))) short;

__device__ __forceinline__ short f2bf(float f) {
  __hip_bfloat16 h = __float2bfloat16(f);     // RTNE; pairs compile to v_cvt_pk_bf16_f32
  return *reinterpret_cast<short*>(&h);
}

__device__ __forceinline__ f32x4 ntload4(const float* p) {
  return __builtin_nontemporal_load(reinterpret_cast<const f32x4*>(p));
}

__device__ __forceinline__ s16x8 pack8(const f32x4 a, const f32x4 b) {
  s16x8 r;
  r[0] = f2bf(a[0]); r[1] = f2bf(a[1]); r[2] = f2bf(a[2]); r[3] = f2bf(a[3]);
  r[4] = f2bf(b[0]); r[5] = f2bf(b[1]); r[6] = f2bf(b[2]); r[7] = f2bf(b[3]);
  return r;
}

// 16-lane butterfly reduce via DPP (VALU-only; no LDS-pipe traffic).
__device__ __forceinline__ float dpp_red16(float x) {
  x += __int_as_float(__builtin_amdgcn_update_dpp(0, __float_as_int(x), 0xB1, 0xF, 0xF, true));  // xor 1
  x += __int_as_float(__builtin_amdgcn_update_dpp(0, __float_as_int(x), 0x4E, 0xF, 0xF, true));  // xor 2
  x += __int_as_float(__builtin_amdgcn_update_dpp(0, __float_as_int(x), 0x141, 0xF, 0xF, true)); // xor 4
  x += __int_as_float(__builtin_amdgcn_update_dpp(0, __float_as_int(x), 0x140, 0xF, 0xF, true)); // xor 8
  return x;
}

// ---------------- weight prep ----------------
// Emits MFMA-B-fragment-layout bf16 weights:
//   flat: b*65536 + (n>>4)*4096 + (k>>5)*512 + (((k>>3)&3)*16 + (n&15))*8 + (k&7)
// 0: Wq = Wcs@Wc1   1: Wqc = Wcs@Wc2   2: Wc1   3: Wc2   4: Anti1   5: Anti2
__global__ void prep_kernel(const float* __restrict__ Wc, const float* __restrict__ bc,
                            const float* __restrict__ Wcs, const float* __restrict__ Wanti,
                            short* __restrict__ Wt, float* __restrict__ bq) {
  __shared__ float wrow[FEATN];
  __shared__ float red[FEATN];
  const int n = blockIdx.x, k = threadIdx.x;
  wrow[k] = Wcs[n * FEATN + k];
  __syncthreads();
  float a0 = 0.f, a1 = 0.f;
  #pragma unroll 8
  for (int j = 0; j < FEATN; ++j) {
    const float w = wrow[j];
    a0 += w * Wc[j * 512 + k];
    a1 += w * Wc[j * 512 + 256 + k];
  }
  red[k] = wrow[k] * bc[k];
  __syncthreads();
  for (int off = 128; off > 0; off >>= 1) {
    if (k < off) red[k] += red[k + off];
    __syncthreads();
  }
  if (k == 0) bq[n] = red[0];
  const int fo = (n >> 4) * 4096 + (k >> 5) * 512 + (((k >> 3) & 3) * 16 + (n & 15)) * 8 + (k & 7);
  Wt[0 * 65536 + fo] = f2bf(a0);
  Wt[1 * 65536 + fo] = f2bf(a1);
  Wt[2 * 65536 + fo] = f2bf(Wc[n * 512 + k]);
  Wt[3 * 65536 + fo] = f2bf(Wc[n * 512 + 256 + k]);
  Wt[4 * 65536 + fo] = f2bf(Wanti[n * 512 + k]);
  Wt[5 * 65536 + fo] = f2bf(Wanti[n * 512 + 256 + k]);
}

// ---------------- fused recurrence + output kernel ----------------
// R19 schedule; waves reshaped to 2 row-groups x 8 col-groups (32x32 tiles,
// m=2 x nn=2): each LDS a-frag read feeds 4 MFMAs -> 48 reads/wave/step.
__global__ __launch_bounds__(1024, 4)
void chain_kernel(const float* __restrict__ x, const float* __restrict__ endi,
                  const short* __restrict__ Wt, const float* __restrict__ bq,
                  const float* __restrict__ bc, const float* __restrict__ Wout,
                  const float* __restrict__ bout, float* __restrict__ out) {
  __shared__ short sbuf[2 * TILE];               // 67584 B ping-pong bf16 tiles
  __shared__ float redP[MT][9];                  // 2304 B (8 col-groups + pad)
  __shared__ float selP[MT][17];                 // 4352 B (8*2 + pad)
  __shared__ float cpL[MT], cumL[MT], seL[MT], csL[MT], eiL[MT];   // 1280 B

  const int tid  = (int)threadIdx.x;
  const int lane = tid & 63;
  const int wave = tid >> 6;                     // 0..15
  const int lr   = lane & 15;
  const int lh   = lane >> 4;
  const int rg   = wave >> 3;                    // row group (0..1) -> rows rg*32..rg*32+31
  const int cg   = wave & 7;                     // col group (0..7) -> cols cg*32..cg*32+31
  const int r0   = (int)blockIdx.x * MT;

  if (tid < MT) { cpL[tid] = 1.f; cumL[tid] = 0.f; seL[tid] = 0.f; }
  for (int i = tid; i < MT * 17; i += 1024) (&selP[0][0])[i] = 0.f;

  // stage x0 into both slots (s0 == x_t at t=0): 8 bf16/thread, 2 iters, b128
  #pragma unroll
  for (int i = 0; i < 2; ++i) {
    const int f = i * 8192 + tid * 8;
    const int row = f >> 8, col = f & 255;
    const float* src = &x[(size_t)(r0 + row) * XROW + col];
    const s16x8 b = pack8(ntload4(src), ntload4(src + 4));
    *reinterpret_cast<s16x8*>(&sbuf[row * LDST + col]) = b;
    *reinterpret_cast<s16x8*>(&sbuf[TILE + row * LDST + col]) = b;
  }

  const int wc0 = cg * 32 + lr;                  // nn=0 col; nn=1 adds 16
  const short* wfb = Wt + cg * 8192 + lane * 8;  // fragment base (2 nn tiles at +0,+4096)
  const int abase = (rg * 32 + lr) * LDST + lh * 8;
  const float bqv0 = bq[wc0], bqv1 = bq[wc0 + 16];
  const float bcv0 = bc[wc0], bcv1 = bc[wc0 + 16];
  const float wo00 = Wout[256 + wc0], wo01 = Wout[256 + wc0 + 16];
  const float wo10 = Wout[768 + wc0], wo11 = Wout[768 + wc0 + 16];
  const f32x4 fzero = {0.f, 0.f, 0.f, 0.f};

  // s state: sreg[m][nn][e] = s[row = rg*32+m*16+lh*4+e][col = cg*32+nn*16+lr]
  float sreg[2][2][4];
  #pragma unroll
  for (int m = 0; m < 2; ++m)
    #pragma unroll
    for (int nn = 0; nn < 2; ++nn)
      #pragma unroll
      for (int e = 0; e < 4; ++e)
        sreg[m][nn][e] = x[(size_t)(r0 + rg * 32 + m * 16 + lh * 4 + e) * XROW + cg * 32 + nn * 16 + lr];

  __syncthreads();

  for (int t = 0; t < NSTEP; ++t) {
    const int so = (t & 1) * TILE;               // holds s_t (then x_{t+1})
    const int xo = ((t + 1) & 1) * TILE;         // holds x_t (then s_{t+1})

    // ---- sweep1 (fused): AccA = s@WqT + xt@WqcT ; AccB = s@Wc1T ;
    //      AccN = xt@Anti1T   (each a-frag read feeds 4 MFMAs) ----
    f32x4 AccA[2][2], AccB[2][2], AccN[2][2];
    #pragma unroll
    for (int m = 0; m < 2; ++m)
      #pragma unroll
      for (int nn = 0; nn < 2; ++nn) { AccA[m][nn] = fzero; AccB[m][nn] = fzero; AccN[m][nn] = fzero; }

    #pragma unroll 1
    for (int ks = 0; ks < 8; ++ks) {
      const short* p = wfb + ks * 512;
      {   // sub-phase A: s-operand matrices
        s16x8 b0[2], b2[2];
        #pragma unroll
        for (int nn = 0; nn < 2; ++nn) {
          b0[nn] = *reinterpret_cast<const s16x8*>(p + nn * 4096 + 0 * 65536);
          b2[nn] = *reinterpret_cast<const s16x8*>(p + nn * 4096 + 2 * 65536);
        }
        #pragma unroll
        for (int m = 0; m < 2; ++m) {
          const s16x8 a_s = *reinterpret_cast<const s16x8*>(&sbuf[so + abase + m * (16 * LDST) + ks * 32]);
          #pragma unroll
          for (int nn = 0; nn < 2; ++nn) {
            AccA[m][nn] = __builtin_amdgcn_mfma_f32_16x16x32_bf16(a_s, b0[nn], AccA[m][nn], 0, 0, 0);
            AccB[m][nn] = __builtin_amdgcn_mfma_f32_16x16x32_bf16(a_s, b2[nn], AccB[m][nn], 0, 0, 0);
          }
        }
      }
      {   // sub-phase B: x_t-operand matrices
        s16x8 b1[2], b4[2];
        #pragma unroll
        for (int nn = 0; nn < 2; ++nn) {
          b1[nn] = *reinterpret_cast<const s16x8*>(p + nn * 4096 + 1 * 65536);
          b4[nn] = *reinterpret_cast<const s16x8*>(p + nn * 4096 + 4 * 65536);
        }
        #pragma unroll
        for (int m = 0; m < 2; ++m) {
          const s16x8 a_x = *reinterpret_cast<const s16x8*>(&sbuf[xo + abase + m * (16 * LDST) + ks * 32]);
          #pragma unroll
          for (int nn = 0; nn < 2; ++nn) {
            AccA[m][nn] = __builtin_amdgcn_mfma_f32_16x16x32_bf16(a_x, b1[nn], AccA[m][nn], 0, 0, 0);
            AccN[m][nn] = __builtin_amdgcn_mfma_f32_16x16x32_bf16(a_x, b4[nn], AccN[m][nn], 0, 0, 0);
          }
        }
      }
    }
    __syncthreads();   // B1: all s-slot AND x_t-slot reads done

    // ---- stage x_{t+1} into the s-slot (transient b128) ----
    #pragma unroll
    for (int i = 0; i < 2; ++i) {
      const int f = i * 8192 + tid * 8;
      const int row = f >> 8, col = f & 255;
      const float* src = &x[(size_t)(r0 + row) * XROW + (t + 1) * FEATN + col];
      const s16x8 b = pack8(ntload4(src), ntload4(src + 4));
      *reinterpret_cast<s16x8*>(&sbuf[so + row * LDST + col]) = b;
    }
    __syncthreads();   // B2: x_{t+1} visible

    // ---- sweep2 (fused): AccB += x_{t+1}@Wc2T ; AccN += x_{t+1}@Anti2T ----
    #pragma unroll 1
    for (int ks = 0; ks < 8; ++ks) {
      const short* p = wfb + ks * 512;
      s16x8 b3[2], b5[2];
      #pragma unroll
      for (int nn = 0; nn < 2; ++nn) {
        b3[nn] = *reinterpret_cast<const s16x8*>(p + nn * 4096 + 3 * 65536);
        b5[nn] = *reinterpret_cast<const s16x8*>(p + nn * 4096 + 5 * 65536);
      }
      #pragma unroll
      for (int m = 0; m < 2; ++m) {
        const s16x8 a_n = *reinterpret_cast<const s16x8*>(&sbuf[so + abase + m * (16 * LDST) + ks * 32]);
        #pragma unroll
        for (int nn = 0; nn < 2; ++nn) {
          AccB[m][nn] = __builtin_amdgcn_mfma_f32_16x16x32_bf16(a_n, b3[nn], AccB[m][nn], 0, 0, 0);
          AccN[m][nn] = __builtin_amdgcn_mfma_f32_16x16x32_bf16(a_n, b5[nn], AccN[m][nn], 0, 0, 0);
        }
      }
    }

    // ---- dot: sum over this wave's 32 cols via in-register nn-sum + DPP ----
    #pragma unroll
    for (int m = 0; m < 2; ++m) {
      #pragma unroll
      for (int e = 0; e < 4; ++e) {
        float p = (AccA[m][0][e] + bqv0) * (AccB[m][0][e] + bcv0)
                + (AccA[m][1][e] + bqv1) * (AccB[m][1][e] + bcv1);
        p = dpp_red16(p);
        if (lr == 0) redP[rg * 32 + m * 16 + lh * 4 + e][cg] = p;
      }
    }
    __syncthreads();   // B3: redP visible

    // cs/cumprod bookkeeping (tid<64)
    if (tid < MT) {
      float d = 0.f;
      #pragma unroll
      for (int w = 0; w < 8; ++w) d += redP[tid][w];
      const float cs = 1.f / (1.f + __expf(-d));
      const float cp = cpL[tid] * cs;
      cpL[tid] = cp;
      const float ei = endi[(size_t)(r0 + tid) * 8 + (t + 1)];
      cumL[tid] += cp * ei;
      seL[tid] += ei;
      csL[tid] = cs;
      eiL[tid] = ei;
    }
    __syncthreads();   // B4: csL/eiL visible

    // ---- update: s += tanh(cs*AccN); selP projection; s_{t+1} -> x_t slot ----
    #pragma unroll
    for (int m = 0; m < 2; ++m) {
      #pragma unroll
      for (int e = 0; e < 4; ++e) {
        const int row = rg * 32 + m * 16 + lh * 4 + e;
        const float cs = csL[row];
        float sn2[2];
        #pragma unroll
        for (int nn = 0; nn < 2; ++nn) {
          const float ag = cs * AccN[m][nn][e];
          const float ex = __expf(2.f * ag);
          const float th = 1.f - 2.f / (ex + 1.f);
          const float sn = sreg[m][nn][e] + th;
          sreg[m][nn][e] = sn;
          sn2[nn] = sn;
          sbuf[xo + row * LDST + (cg * 32 + nn * 16 + lr)] = f2bf(sn);
        }
        if (eiL[row] != 0.f) {                   // uniform across the lr group
          const float p0 = dpp_red16(sn2[0] * wo00 + sn2[1] * wo01);
          const float p1 = dpp_red16(sn2[0] * wo10 + sn2[1] * wo11);
          if (lr == 0) { selP[row][cg * 2] = p0; selP[row][cg * 2 + 1] = p1; }
        }
      }
    }
    __syncthreads();   // B5: s_{t+1} visible for next sweep1
  }

  // final: one group of 8 rows per wave (waves 0..7), softmax over cum, combine
  if (wave < 8) {
    const int g = wave;
    const int rowb = g * 8;
    float c[8];
    float mx = -3.4e38f;
    #pragma unroll
    for (int m = 0; m < 8; ++m) {
      c[m] = cumL[rowb + m] - (1.f - seL[rowb + m]) * 10000.f;
      mx = fmaxf(mx, c[m]);
    }
    float sum = 0.f;
    float wgt[8];
    #pragma unroll
    for (int m = 0; m < 8; ++m) { wgt[m] = __expf(c[m] - mx); sum += wgt[m]; }
    const float inv = 1.f / sum;
    float up0 = 0.f, up1 = 0.f;
    #pragma unroll
    for (int m = 0; m < 8; ++m) {
      float s0 = 0.f, s1 = 0.f;
      #pragma unroll
      for (int w = 0; w < 8; ++w) {
        s0 += selP[rowb + m][w * 2];
        s1 += selP[rowb + m][w * 2 + 1];
      }
      const float wm = wgt[m] * inv;
      up0 += wm * s0; up1 += wm * s1;
    }
    const int d = lane * 4;
    const float4 xv  = *reinterpret_cast<const float4*>(&x[(size_t)(r0 + rowb) * XROW + d]);
    const float4 w00 = *reinterpret_cast<const float4*>(&Wout[d]);
    const float4 w10 = *reinterpret_cast<const float4*>(&Wout[512 + d]);
    float o0 = xv.x * w00.x + xv.y * w00.y + xv.z * w00.z + xv.w * w00.w;
    float o1 = xv.x * w10.x + xv.y * w10.y + xv.z * w10.z + xv.w * w10.w;
    #pragma unroll
    for (int off = 1; off < 64; off <<= 1) {
      o0 += __shfl_xor(o0, off);
      o1 += __shfl_xor(o1, off);
    }
    if (lane == 0) {
      const int n = (int)blockIdx.x * 8 + g;
      out[n * 2 + 0] = o0 + up0 + bout[0];
      out[n * 2 + 1] = o1 + up1 + bout[1];
    }
  }
}

extern "C" void kernel_launch(void* const* d_in, const int* in_sizes, int n_in,
                              void* d_out, int out_size, void* d_ws, size_t ws_size,
                              hipStream_t stream) {
  const float* x     = (const float*)d_in[0];
  const float* endi  = (const float*)d_in[1];
  // d_in[2] = max_chain (==8, hard-coded)
  const float* Wc    = (const float*)d_in[3];
  const float* bc    = (const float*)d_in[4];
  const float* Wcs   = (const float*)d_in[5];
  const float* Wanti = (const float*)d_in[6];
  const float* Wout  = (const float*)d_in[7];
  const float* bout  = (const float*)d_in[8];
  float* out = (float*)d_out;

  char* ws = (char*)d_ws;
  short* Wt = (short*)ws;                 // 6*256*256*2 = 768 KB (fragment layout)
  float* bq = (float*)(ws + 786432);      // 1 KB

  prep_kernel<<<dim3(256), dim3(256), 0, stream>>>(Wc, bc, Wcs, Wanti, Wt, bq);
  chain_kernel<<<dim3(512), dim3(1024), 0, stream>>>(x, endi, Wt, bq, bc, Wout, bout, out);
}

// Round 21
// 280.786 us; speedup vs baseline: 1.0315x; 1.0315x over previous
//
#include <hip/hip_runtime.h>
#include <hip/hip_bf16.h>

#define FEATN 256
#define XROW  2048      // L*FEAT
#define MT    64        // rows per workgroup
#define NW    16        // waves per workgroup (each owns 16 output cols)
#define LDST  264       // padded LDS row stride (bf16 elems)
#define TILE  (MT * LDST)
#define NSTEP 7

using f32x4 = __attribute__((ext_vector_type(4))) float;
using s16x8 = __attribute__((ext_vector_type(8))) short;

__device__ __forceinline__ short f2bf(float f) {
  __hip_bfloat16 h = __float2bfloat16(f);     // RTNE; pairs compile to v_cvt_pk_bf16_f32
  return *reinterpret_cast<short*>(&h);
}

__device__ __forceinline__ f32x4 ntload4(const float* p) {
  return __builtin_nontemporal_load(reinterpret_cast<const f32x4*>(p));
}

__device__ __forceinline__ s16x8 pack8(const f32x4 a, const f32x4 b) {
  s16x8 r;
  r[0] = f2bf(a[0]); r[1] = f2bf(a[1]); r[2] = f2bf(a[2]); r[3] = f2bf(a[3]);
  r[4] = f2bf(b[0]); r[5] = f2bf(b[1]); r[6] = f2bf(b[2]); r[7] = f2bf(b[3]);
  return r;
}

// 16-lane butterfly reduce via DPP (VALU-only; no LDS-pipe traffic).
__device__ __forceinline__ float dpp_red16(float x) {
  x += __int_as_float(__builtin_amdgcn_update_dpp(0, __float_as_int(x), 0xB1, 0xF, 0xF, true));  // xor 1
  x += __int_as_float(__builtin_amdgcn_update_dpp(0, __float_as_int(x), 0x4E, 0xF, 0xF, true));  // xor 2
  x += __int_as_float(__builtin_amdgcn_update_dpp(0, __float_as_int(x), 0x141, 0xF, 0xF, true)); // xor 4
  x += __int_as_float(__builtin_amdgcn_update_dpp(0, __float_as_int(x), 0x140, 0xF, 0xF, true)); // xor 8
  return x;
}

// ---------------- weight prep ----------------
// Emits MFMA-B-fragment-layout bf16 weights:
//   flat: b*65536 + (n>>4)*4096 + (k>>5)*512 + (((k>>3)&3)*16 + (n&15))*8 + (k&7)
// 0: Wq = Wcs@Wc1   1: Wqc = Wcs@Wc2   2: Wc1   3: Wc2   4: Anti1   5: Anti2
__global__ void prep_kernel(const float* __restrict__ Wc, const float* __restrict__ bc,
                            const float* __restrict__ Wcs, const float* __restrict__ Wanti,
                            short* __restrict__ Wt, float* __restrict__ bq) {
  __shared__ float wrow[FEATN];
  __shared__ float red[FEATN];
  const int n = blockIdx.x, k = threadIdx.x;
  wrow[k] = Wcs[n * FEATN + k];
  __syncthreads();
  float a0 = 0.f, a1 = 0.f;
  #pragma unroll 8
  for (int j = 0; j < FEATN; ++j) {
    const float w = wrow[j];
    a0 += w * Wc[j * 512 + k];
    a1 += w * Wc[j * 512 + 256 + k];
  }
  red[k] = wrow[k] * bc[k];
  __syncthreads();
  for (int off = 128; off > 0; off >>= 1) {
    if (k < off) red[k] += red[k + off];
    __syncthreads();
  }
  if (k == 0) bq[n] = red[0];
  const int fo = (n >> 4) * 4096 + (k >> 5) * 512 + (((k >> 3) & 3) * 16 + (n & 15)) * 8 + (k & 7);
  Wt[0 * 65536 + fo] = f2bf(a0);
  Wt[1 * 65536 + fo] = f2bf(a1);
  Wt[2 * 65536 + fo] = f2bf(Wc[n * 512 + k]);
  Wt[3 * 65536 + fo] = f2bf(Wc[n * 512 + 256 + k]);
  Wt[4 * 65536 + fo] = f2bf(Wanti[n * 512 + k]);
  Wt[5 * 65536 + fo] = f2bf(Wanti[n * 512 + 256 + k]);
}

// ---------------- fused recurrence + output kernel ----------------
// R19 structure; x_{t+1} staging loads issued at TOP of step (held in regs
// through sweep1), so HBM/L3 latency hides under sweep1's MFMAs (T14).
__global__ __launch_bounds__(1024, 4)
void chain_kernel(const float* __restrict__ x, const float* __restrict__ endi,
                  const short* __restrict__ Wt, const float* __restrict__ bq,
                  const float* __restrict__ bc, const float* __restrict__ Wout,
                  const float* __restrict__ bout, float* __restrict__ out) {
  __shared__ short sbuf[2 * TILE];               // 67584 B ping-pong bf16 tiles
  __shared__ float redP[MT][NW];                 // 4096 B
  __shared__ float selP[MT][2 * NW];             // 8192 B
  __shared__ float cpL[MT], cumL[MT], seL[MT], csL[MT], eiL[MT];   // 1280 B

  const int tid  = (int)threadIdx.x;
  const int lane = tid & 63;
  const int wave = tid >> 6;                     // 0..15
  const int lr   = lane & 15;
  const int lh   = lane >> 4;
  const int r0   = (int)blockIdx.x * MT;

  if (tid < MT) { cpL[tid] = 1.f; cumL[tid] = 0.f; seL[tid] = 0.f; }
  #pragma unroll
  for (int i = 0; i < 2; ++i) (&selP[0][0])[i * 1024 + tid] = 0.f;

  // stage x0 into both slots (s0 == x_t at t=0): 8 bf16/thread, 2 iters, b128
  #pragma unroll
  for (int i = 0; i < 2; ++i) {
    const int f = i * 8192 + tid * 8;
    const int row = f >> 8, col = f & 255;
    const float* src = &x[(size_t)(r0 + row) * XROW + col];
    const s16x8 b = pack8(ntload4(src), ntload4(src + 4));
    *reinterpret_cast<s16x8*>(&sbuf[row * LDST + col]) = b;
    *reinterpret_cast<s16x8*>(&sbuf[TILE + row * LDST + col]) = b;
  }

  const int wcol = wave * 16 + lr;               // this wave's output col
  const short* wfb = Wt + wave * 4096 + lane * 8;   // fragment-layout base
  const int abase = lr * LDST + lh * 8;
  const float bqv = bq[wcol];
  const float bcv = bc[wcol];
  const float wo0 = Wout[256 + wcol];
  const float wo1 = Wout[768 + wcol];
  const f32x4 fzero = {0.f, 0.f, 0.f, 0.f};

  // s state in registers: sreg[m][e] = s[row = m*16+lh*4+e][col = wcol]
  float sreg[4][4];
  #pragma unroll
  for (int m = 0; m < 4; ++m)
    #pragma unroll
    for (int e = 0; e < 4; ++e)
      sreg[m][e] = x[(size_t)(r0 + m * 16 + lh * 4 + e) * XROW + wcol];

  __syncthreads();

  for (int t = 0; t < NSTEP; ++t) {
    const int so = (t & 1) * TILE;               // holds s_t (then x_{t+1})
    const int xo = ((t + 1) & 1) * TILE;         // holds x_t (then s_{t+1})

    // ---- T14: issue x_{t+1} loads NOW; hold in regs through sweep1 ----
    f32x4 pf[2][2];
    #pragma unroll
    for (int i = 0; i < 2; ++i) {
      const int f = i * 8192 + tid * 8;
      const float* src = &x[(size_t)(r0 + (f >> 8)) * XROW + (t + 1) * FEATN + (f & 255)];
      pf[i][0] = ntload4(src);
      pf[i][1] = ntload4(src + 4);
    }

    // ---- sweep1 (fused): AccA = s@WqT + xt@WqcT ; AccB = s@Wc1T ;
    //      AccN = xt@Anti1T   (each a-frag read once) ----
    f32x4 AccA[4], AccB[4], AccN[4];
    #pragma unroll
    for (int m = 0; m < 4; ++m) { AccA[m] = fzero; AccB[m] = fzero; AccN[m] = fzero; }

    #pragma unroll 1
    for (int ks = 0; ks < 8; ++ks) {
      const short* p = wfb + ks * 512;
      {   // sub-phase A: s-operand matrices
        const s16x8 b0 = *reinterpret_cast<const s16x8*>(p + 0 * 65536);
        const s16x8 b2 = *reinterpret_cast<const s16x8*>(p + 2 * 65536);
        #pragma unroll
        for (int m = 0; m < 4; ++m) {
          const s16x8 a_s = *reinterpret_cast<const s16x8*>(&sbuf[so + abase + m * (16 * LDST) + ks * 32]);
          AccA[m] = __builtin_amdgcn_mfma_f32_16x16x32_bf16(a_s, b0, AccA[m], 0, 0, 0);
          AccB[m] = __builtin_amdgcn_mfma_f32_16x16x32_bf16(a_s, b2, AccB[m], 0, 0, 0);
        }
      }
      {   // sub-phase B: x_t-operand matrices
        const s16x8 b1 = *reinterpret_cast<const s16x8*>(p + 1 * 65536);
        const s16x8 b4 = *reinterpret_cast<const s16x8*>(p + 4 * 65536);
        #pragma unroll
        for (int m = 0; m < 4; ++m) {
          const s16x8 a_x = *reinterpret_cast<const s16x8*>(&sbuf[xo + abase + m * (16 * LDST) + ks * 32]);
          AccA[m] = __builtin_amdgcn_mfma_f32_16x16x32_bf16(a_x, b1, AccA[m], 0, 0, 0);
          AccN[m] = __builtin_amdgcn_mfma_f32_16x16x32_bf16(a_x, b4, AccN[m], 0, 0, 0);
        }
      }
    }
    __syncthreads();   // B1: all s-slot AND x_t-slot reads done

    // ---- write staged x_{t+1} into the s-slot (loads already landed) ----
    #pragma unroll
    for (int i = 0; i < 2; ++i) {
      const int f = i * 8192 + tid * 8;
      const int row = f >> 8, col = f & 255;
      *reinterpret_cast<s16x8*>(&sbuf[so + row * LDST + col]) = pack8(pf[i][0], pf[i][1]);
    }
    __syncthreads();   // B2: x_{t+1} visible

    // ---- sweep2 (fused): AccB += x_{t+1}@Wc2T ; AccN += x_{t+1}@Anti2T ----
    #pragma unroll 1
    for (int ks = 0; ks < 8; ++ks) {
      const short* p = wfb + ks * 512;
      const s16x8 b3 = *reinterpret_cast<const s16x8*>(p + 3 * 65536);
      const s16x8 b5 = *reinterpret_cast<const s16x8*>(p + 5 * 65536);
      #pragma unroll
      for (int m = 0; m < 4; ++m) {
        const s16x8 a_n = *reinterpret_cast<const s16x8*>(&sbuf[so + abase + m * (16 * LDST) + ks * 32]);
        AccB[m] = __builtin_amdgcn_mfma_f32_16x16x32_bf16(a_n, b3, AccB[m], 0, 0, 0);
        AccN[m] = __builtin_amdgcn_mfma_f32_16x16x32_bf16(a_n, b5, AccN[m], 0, 0, 0);
      }
    }

    // ---- dot: sum_d (AccA+bq)*(AccB+bc) via DPP butterfly ----
    #pragma unroll
    for (int m = 0; m < 4; ++m) {
      #pragma unroll
      for (int e = 0; e < 4; ++e) {
        const float p = dpp_red16((AccA[m][e] + bqv) * (AccB[m][e] + bcv));
        if (lr == 0) redP[m * 16 + lh * 4 + e][wave] = p;
      }
    }
    __syncthreads();   // B3: redP visible

    // cs/cumprod bookkeeping (tid<64)
    if (tid < MT) {
      float d = 0.f;
      #pragma unroll
      for (int w = 0; w < NW; ++w) d += redP[tid][w];
      const float cs = 1.f / (1.f + __expf(-d));
      const float cp = cpL[tid] * cs;
      cpL[tid] = cp;
      const float ei = endi[(size_t)(r0 + tid) * 8 + (t + 1)];
      cumL[tid] += cp * ei;
      seL[tid] += ei;
      csL[tid] = cs;
      eiL[tid] = ei;
    }
    __syncthreads();   // B4: csL/eiL visible

    // ---- update: s += tanh(cs*AccN); selP projection; s_{t+1} -> x_t slot ----
    #pragma unroll
    for (int m = 0; m < 4; ++m) {
      #pragma unroll
      for (int e = 0; e < 4; ++e) {
        const int row = m * 16 + lh * 4 + e;
        const float cs = csL[row];
        const float ag = cs * AccN[m][e];
        const float ex = __expf(2.f * ag);
        const float th = 1.f - 2.f / (ex + 1.f);
        const float sn = sreg[m][e] + th;
        sreg[m][e] = sn;
        sbuf[xo + row * LDST + wcol] = f2bf(sn);
        if (eiL[row] != 0.f) {                   // uniform across the lr group
          const float p0 = dpp_red16(sn * wo0);
          const float p1 = dpp_red16(sn * wo1);
          if (lr == 0) { selP[row][wave * 2] = p0; selP[row][wave * 2 + 1] = p1; }
        }
      }
    }
    __syncthreads();   // B5: s_{t+1} visible for next sweep1
  }

  // final: one group of 8 rows per wave (waves 0..7), softmax over cum, combine
  if (wave < 8) {
    const int g = wave;
    const int rowb = g * 8;
    float c[8];
    float mx = -3.4e38f;
    #pragma unroll
    for (int m = 0; m < 8; ++m) {
      c[m] = cumL[rowb + m] - (1.f - seL[rowb + m]) * 10000.f;
      mx = fmaxf(mx, c[m]);
    }
    float sum = 0.f;
    float wgt[8];
    #pragma unroll
    for (int m = 0; m < 8; ++m) { wgt[m] = __expf(c[m] - mx); sum += wgt[m]; }
    const float inv = 1.f / sum;
    float up0 = 0.f, up1 = 0.f;
    #pragma unroll
    for (int m = 0; m < 8; ++m) {
      float s0 = 0.f, s1 = 0.f;
      #pragma unroll
      for (int w = 0; w < NW; ++w) {
        s0 += selP[rowb + m][w * 2];
        s1 += selP[rowb + m][w * 2 + 1];
      }
      const float wm = wgt[m] * inv;
      up0 += wm * s0; up1 += wm * s1;
    }
    const int d = lane * 4;
    const float4 xv  = *reinterpret_cast<const float4*>(&x[(size_t)(r0 + rowb) * XROW + d]);
    const float4 w00 = *reinterpret_cast<const float4*>(&Wout[d]);
    const float4 w10 = *reinterpret_cast<const float4*>(&Wout[512 + d]);
    float o0 = xv.x * w00.x + xv.y * w00.y + xv.z * w00.z + xv.w * w00.w;
    float o1 = xv.x * w10.x + xv.y * w10.y + xv.z * w10.z + xv.w * w10.w;
    #pragma unroll
    for (int off = 1; off < 64; off <<= 1) {
      o0 += __shfl_xor(o0, off);
      o1 += __shfl_xor(o1, off);
    }
    if (lane == 0) {
      const int n = (int)blockIdx.x * 8 + g;
      out[n * 2 + 0] = o0 + up0 + bout[0];
      out[n * 2 + 1] = o1 + up1 + bout[1];
    }
  }
}

extern "C" void kernel_launch(void* const* d_in, const int* in_sizes, int n_in,
                              void* d_out, int out_size, void* d_ws, size_t ws_size,
                              hipStream_t stream) {
  const float* x     = (const float*)d_in[0];
  const float* endi  = (const float*)d_in[1];
  // d_in[2] = max_chain (==8, hard-coded)
  const float* Wc    = (const float*)d_in[3];
  const float* bc    = (const float*)d_in[4];
  const float* Wcs   = (const float*)d_in[5];
  const float* Wanti = (const float*)d_in[6];
  const float* Wout  = (const float*)d_in[7];
  const float* bout  = (const float*)d_in[8];
  float* out = (float*)d_out;

  char* ws = (char*)d_ws;
  short* Wt = (short*)ws;                 // 6*256*256*2 = 768 KB (fragment layout)
  float* bq = (float*)(ws + 786432);      // 1 KB

  prep_kernel<<<dim3(256), dim3(256), 0, stream>>>(Wc, bc, Wcs, Wanti, Wt, bq);
  chain_kernel<<<dim3(512), dim3(1024), 0, stream>>>(x, endi, Wt, bq, bc, Wout, bout, out);
}

// Round 22
// 273.558 us; speedup vs baseline: 1.0587x; 1.0264x over previous
//
#include <hip/hip_runtime.h>
#include <hip/hip_bf16.h>

#define FEATN 256
#define XROW  2048      // L*FEAT
#define MT    64        // rows per workgroup
#define NW    16        // waves per workgroup (each owns 16 output cols)
#define LDST  264       // padded LDS row stride (bf16 elems)
#define TILE  (MT * LDST)
#define NSTEP 7

using f32x4 = __attribute__((ext_vector_type(4))) float;
using s16x8 = __attribute__((ext_vector_type(8))) short;

__device__ __forceinline__ short f2bf(float f) {
  __hip_bfloat16 h = __float2bfloat16(f);     // RTNE; pairs compile to v_cvt_pk_bf16_f32
  return *reinterpret_cast<short*>(&h);
}

__device__ __forceinline__ f32x4 ntload4(const float* p) {
  return __builtin_nontemporal_load(reinterpret_cast<const f32x4*>(p));
}

__device__ __forceinline__ s16x8 pack8(const f32x4 a, const f32x4 b) {
  s16x8 r;
  r[0] = f2bf(a[0]); r[1] = f2bf(a[1]); r[2] = f2bf(a[2]); r[3] = f2bf(a[3]);
  r[4] = f2bf(b[0]); r[5] = f2bf(b[1]); r[6] = f2bf(b[2]); r[7] = f2bf(b[3]);
  return r;
}

// 16-lane butterfly reduce via DPP (VALU-only; no LDS-pipe traffic).
__device__ __forceinline__ float dpp_red16(float x) {
  x += __int_as_float(__builtin_amdgcn_update_dpp(0, __float_as_int(x), 0xB1, 0xF, 0xF, true));  // xor 1
  x += __int_as_float(__builtin_amdgcn_update_dpp(0, __float_as_int(x), 0x4E, 0xF, 0xF, true));  // xor 2
  x += __int_as_float(__builtin_amdgcn_update_dpp(0, __float_as_int(x), 0x141, 0xF, 0xF, true)); // xor 4
  x += __int_as_float(__builtin_amdgcn_update_dpp(0, __float_as_int(x), 0x140, 0xF, 0xF, true)); // xor 8
  return x;
}

// ---------------- weight prep ----------------
// Emits MFMA-B-fragment-layout bf16 weights:
//   flat: b*65536 + (n>>4)*4096 + (k>>5)*512 + (((k>>3)&3)*16 + (n&15))*8 + (k&7)
// 0: Wq = Wcs@Wc1   1: Wqc = Wcs@Wc2   2: Wc1   3: Wc2   4: Anti1   5: Anti2
__global__ void prep_kernel(const float* __restrict__ Wc, const float* __restrict__ bc,
                            const float* __restrict__ Wcs, const float* __restrict__ Wanti,
                            short* __restrict__ Wt, float* __restrict__ bq) {
  __shared__ float wrow[FEATN];
  __shared__ float red[FEATN];
  const int n = blockIdx.x, k = threadIdx.x;
  wrow[k] = Wcs[n * FEATN + k];
  __syncthreads();
  float a0 = 0.f, a1 = 0.f;
  #pragma unroll 8
  for (int j = 0; j < FEATN; ++j) {
    const float w = wrow[j];
    a0 += w * Wc[j * 512 + k];
    a1 += w * Wc[j * 512 + 256 + k];
  }
  red[k] = wrow[k] * bc[k];
  __syncthreads();
  for (int off = 128; off > 0; off >>= 1) {
    if (k < off) red[k] += red[k + off];
    __syncthreads();
  }
  if (k == 0) bq[n] = red[0];
  const int fo = (n >> 4) * 4096 + (k >> 5) * 512 + (((k >> 3) & 3) * 16 + (n & 15)) * 8 + (k & 7);
  Wt[0 * 65536 + fo] = f2bf(a0);
  Wt[1 * 65536 + fo] = f2bf(a1);
  Wt[2 * 65536 + fo] = f2bf(Wc[n * 512 + k]);
  Wt[3 * 65536 + fo] = f2bf(Wc[n * 512 + 256 + k]);
  Wt[4 * 65536 + fo] = f2bf(Wanti[n * 512 + k]);
  Wt[5 * 65536 + fo] = f2bf(Wanti[n * 512 + 256 + k]);
}

// ---------------- fused recurrence + output kernel ----------------
// R19 base; sweep loops manually 2-step pipelined: the leading b-frag pair
// (b0/b2, resp. b3/b5) for step k+1 is loaded BEFORE step k's MFMAs, using
// a 16-reg ping-pong that fits the remaining register slack.
__global__ __launch_bounds__(1024, 4)
void chain_kernel(const float* __restrict__ x, const float* __restrict__ endi,
                  const short* __restrict__ Wt, const float* __restrict__ bq,
                  const float* __restrict__ bc, const float* __restrict__ Wout,
                  const float* __restrict__ bout, float* __restrict__ out) {
  __shared__ short sbuf[2 * TILE];               // 67584 B ping-pong bf16 tiles
  __shared__ float redP[MT][NW];                 // 4096 B
  __shared__ float selP[MT][2 * NW];             // 8192 B
  __shared__ float cpL[MT], cumL[MT], seL[MT], csL[MT], eiL[MT];   // 1280 B

  const int tid  = (int)threadIdx.x;
  const int lane = tid & 63;
  const int wave = tid >> 6;                     // 0..15
  const int lr   = lane & 15;
  const int lh   = lane >> 4;
  const int r0   = (int)blockIdx.x * MT;

  if (tid < MT) { cpL[tid] = 1.f; cumL[tid] = 0.f; seL[tid] = 0.f; }
  #pragma unroll
  for (int i = 0; i < 2; ++i) (&selP[0][0])[i * 1024 + tid] = 0.f;

  // stage x0 into both slots (s0 == x_t at t=0): 8 bf16/thread, 2 iters, b128
  #pragma unroll
  for (int i = 0; i < 2; ++i) {
    const int f = i * 8192 + tid * 8;
    const int row = f >> 8, col = f & 255;
    const float* src = &x[(size_t)(r0 + row) * XROW + col];
    const s16x8 b = pack8(ntload4(src), ntload4(src + 4));
    *reinterpret_cast<s16x8*>(&sbuf[row * LDST + col]) = b;
    *reinterpret_cast<s16x8*>(&sbuf[TILE + row * LDST + col]) = b;
  }

  const int wcol = wave * 16 + lr;               // this wave's output col
  const short* wfb = Wt + wave * 4096 + lane * 8;   // fragment-layout base
  const int abase = lr * LDST + lh * 8;
  const float bqv = bq[wcol];
  const float bcv = bc[wcol];
  const float wo0 = Wout[256 + wcol];
  const float wo1 = Wout[768 + wcol];
  const f32x4 fzero = {0.f, 0.f, 0.f, 0.f};

  // s state in registers: sreg[m][e] = s[row = m*16+lh*4+e][col = wcol]
  float sreg[4][4];
  #pragma unroll
  for (int m = 0; m < 4; ++m)
    #pragma unroll
    for (int e = 0; e < 4; ++e)
      sreg[m][e] = x[(size_t)(r0 + m * 16 + lh * 4 + e) * XROW + wcol];

  __syncthreads();

  for (int t = 0; t < NSTEP; ++t) {
    const int so = (t & 1) * TILE;               // holds s_t (then x_{t+1})
    const int xo = ((t + 1) & 1) * TILE;         // holds x_t (then s_{t+1})

    // ---- sweep1 (fused, 2-step SWP): AccA = s@WqT + xt@WqcT ; AccB = s@Wc1T ;
    //      AccN = xt@Anti1T ----
    f32x4 AccA[4], AccB[4], AccN[4];
    #pragma unroll
    for (int m = 0; m < 4; ++m) { AccA[m] = fzero; AccB[m] = fzero; AccN[m] = fzero; }

    s16x8 b0a, b2a, b0b, b2b;
    b0a = *reinterpret_cast<const s16x8*>(wfb + 0 * 65536);
    b2a = *reinterpret_cast<const s16x8*>(wfb + 2 * 65536);
    #pragma unroll 1
    for (int ks = 0; ks < 8; ks += 2) {
      {   // prefetch leading pair for ks+1
        const short* pn = wfb + (ks + 1) * 512;
        b0b = *reinterpret_cast<const s16x8*>(pn + 0 * 65536);
        b2b = *reinterpret_cast<const s16x8*>(pn + 2 * 65536);
      }
      {   // step ks (uses a-set)
        const short* p = wfb + ks * 512;
        #pragma unroll
        for (int m = 0; m < 4; ++m) {
          const s16x8 a_s = *reinterpret_cast<const s16x8*>(&sbuf[so + abase + m * (16 * LDST) + ks * 32]);
          AccA[m] = __builtin_amdgcn_mfma_f32_16x16x32_bf16(a_s, b0a, AccA[m], 0, 0, 0);
          AccB[m] = __builtin_amdgcn_mfma_f32_16x16x32_bf16(a_s, b2a, AccB[m], 0, 0, 0);
        }
        const s16x8 b1 = *reinterpret_cast<const s16x8*>(p + 1 * 65536);
        const s16x8 b4 = *reinterpret_cast<const s16x8*>(p + 4 * 65536);
        #pragma unroll
        for (int m = 0; m < 4; ++m) {
          const s16x8 a_x = *reinterpret_cast<const s16x8*>(&sbuf[xo + abase + m * (16 * LDST) + ks * 32]);
          AccA[m] = __builtin_amdgcn_mfma_f32_16x16x32_bf16(a_x, b1, AccA[m], 0, 0, 0);
          AccN[m] = __builtin_amdgcn_mfma_f32_16x16x32_bf16(a_x, b4, AccN[m], 0, 0, 0);
        }
      }
      {   // prefetch leading pair for ks+2 (wraps harmlessly on last iter)
        const short* pn = wfb + ((ks + 2) & 7) * 512;
        b0a = *reinterpret_cast<const s16x8*>(pn + 0 * 65536);
        b2a = *reinterpret_cast<const s16x8*>(pn + 2 * 65536);
      }
      {   // step ks+1 (uses b-set)
        const int k1 = ks + 1;
        const short* p = wfb + k1 * 512;
        #pragma unroll
        for (int m = 0; m < 4; ++m) {
          const s16x8 a_s = *reinterpret_cast<const s16x8*>(&sbuf[so + abase + m * (16 * LDST) + k1 * 32]);
          AccA[m] = __builtin_amdgcn_mfma_f32_16x16x32_bf16(a_s, b0b, AccA[m], 0, 0, 0);
          AccB[m] = __builtin_amdgcn_mfma_f32_16x16x32_bf16(a_s, b2b, AccB[m], 0, 0, 0);
        }
        const s16x8 b1 = *reinterpret_cast<const s16x8*>(p + 1 * 65536);
        const s16x8 b4 = *reinterpret_cast<const s16x8*>(p + 4 * 65536);
        #pragma unroll
        for (int m = 0; m < 4; ++m) {
          const s16x8 a_x = *reinterpret_cast<const s16x8*>(&sbuf[xo + abase + m * (16 * LDST) + k1 * 32]);
          AccA[m] = __builtin_amdgcn_mfma_f32_16x16x32_bf16(a_x, b1, AccA[m], 0, 0, 0);
          AccN[m] = __builtin_amdgcn_mfma_f32_16x16x32_bf16(a_x, b4, AccN[m], 0, 0, 0);
        }
      }
    }
    __syncthreads();   // B1: all s-slot AND x_t-slot reads done

    // ---- stage x_{t+1} into the s-slot (transient b128) ----
    #pragma unroll
    for (int i = 0; i < 2; ++i) {
      const int f = i * 8192 + tid * 8;
      const int row = f >> 8, col = f & 255;
      const float* src = &x[(size_t)(r0 + row) * XROW + (t + 1) * FEATN + col];
      const s16x8 b = pack8(ntload4(src), ntload4(src + 4));
      *reinterpret_cast<s16x8*>(&sbuf[so + row * LDST + col]) = b;
    }
    __syncthreads();   // B2: x_{t+1} visible

    // ---- sweep2 (fused, 2-step SWP): AccB += x_{t+1}@Wc2T ; AccN += x_{t+1}@Anti2T ----
    s16x8 b3a, b5a, b3b, b5b;
    b3a = *reinterpret_cast<const s16x8*>(wfb + 3 * 65536);
    b5a = *reinterpret_cast<const s16x8*>(wfb + 5 * 65536);
    #pragma unroll 1
    for (int ks = 0; ks < 8; ks += 2) {
      {
        const short* pn = wfb + (ks + 1) * 512;
        b3b = *reinterpret_cast<const s16x8*>(pn + 3 * 65536);
        b5b = *reinterpret_cast<const s16x8*>(pn + 5 * 65536);
      }
      #pragma unroll
      for (int m = 0; m < 4; ++m) {
        const s16x8 a_n = *reinterpret_cast<const s16x8*>(&sbuf[so + abase + m * (16 * LDST) + ks * 32]);
        AccB[m] = __builtin_amdgcn_mfma_f32_16x16x32_bf16(a_n, b3a, AccB[m], 0, 0, 0);
        AccN[m] = __builtin_amdgcn_mfma_f32_16x16x32_bf16(a_n, b5a, AccN[m], 0, 0, 0);
      }
      {
        const short* pn = wfb + ((ks + 2) & 7) * 512;
        b3a = *reinterpret_cast<const s16x8*>(pn + 3 * 65536);
        b5a = *reinterpret_cast<const s16x8*>(pn + 5 * 65536);
      }
      #pragma unroll
      for (int m = 0; m < 4; ++m) {
        const s16x8 a_n = *reinterpret_cast<const s16x8*>(&sbuf[so + abase + m * (16 * LDST) + (ks + 1) * 32]);
        AccB[m] = __builtin_amdgcn_mfma_f32_16x16x32_bf16(a_n, b3b, AccB[m], 0, 0, 0);
        AccN[m] = __builtin_amdgcn_mfma_f32_16x16x32_bf16(a_n, b5b, AccN[m], 0, 0, 0);
      }
    }

    // ---- dot: sum_d (AccA+bq)*(AccB+bc) via DPP butterfly ----
    #pragma unroll
    for (int m = 0; m < 4; ++m) {
      #pragma unroll
      for (int e = 0; e < 4; ++e) {
        const float p = dpp_red16((AccA[m][e] + bqv) * (AccB[m][e] + bcv));
        if (lr == 0) redP[m * 16 + lh * 4 + e][wave] = p;
      }
    }
    __syncthreads();   // B3: redP visible

    // cs/cumprod bookkeeping (tid<64)
    if (tid < MT) {
      float d = 0.f;
      #pragma unroll
      for (int w = 0; w < NW; ++w) d += redP[tid][w];
      const float cs = 1.f / (1.f + __expf(-d));
      const float cp = cpL[tid] * cs;
      cpL[tid] = cp;
      const float ei = endi[(size_t)(r0 + tid) * 8 + (t + 1)];
      cumL[tid] += cp * ei;
      seL[tid] += ei;
      csL[tid] = cs;
      eiL[tid] = ei;
    }
    __syncthreads();   // B4: csL/eiL visible

    // ---- update: s += tanh(cs*AccN); selP projection; s_{t+1} -> x_t slot ----
    #pragma unroll
    for (int m = 0; m < 4; ++m) {
      #pragma unroll
      for (int e = 0; e < 4; ++e) {
        const int row = m * 16 + lh * 4 + e;
        const float cs = csL[row];
        const float ag = cs * AccN[m][e];
        const float ex = __expf(2.f * ag);
        const float th = 1.f - 2.f / (ex + 1.f);
        const float sn = sreg[m][e] + th;
        sreg[m][e] = sn;
        sbuf[xo + row * LDST + wcol] = f2bf(sn);
        if (eiL[row] != 0.f) {                   // uniform across the lr group
          const float p0 = dpp_red16(sn * wo0);
          const float p1 = dpp_red16(sn * wo1);
          if (lr == 0) { selP[row][wave * 2] = p0; selP[row][wave * 2 + 1] = p1; }
        }
      }
    }
    __syncthreads();   // B5: s_{t+1} visible for next sweep1
  }

  // final: one group of 8 rows per wave (waves 0..7), softmax over cum, combine
  if (wave < 8) {
    const int g = wave;
    const int rowb = g * 8;
    float c[8];
    float mx = -3.4e38f;
    #pragma unroll
    for (int m = 0; m < 8; ++m) {
      c[m] = cumL[rowb + m] - (1.f - seL[rowb + m]) * 10000.f;
      mx = fmaxf(mx, c[m]);
    }
    float sum = 0.f;
    float wgt[8];
    #pragma unroll
    for (int m = 0; m < 8; ++m) { wgt[m] = __expf(c[m] - mx); sum += wgt[m]; }
    const float inv = 1.f / sum;
    float up0 = 0.f, up1 = 0.f;
    #pragma unroll
    for (int m = 0; m < 8; ++m) {
      float s0 = 0.f, s1 = 0.f;
      #pragma unroll
      for (int w = 0; w < NW; ++w) {
        s0 += selP[rowb + m][w * 2];
        s1 += selP[rowb + m][w * 2 + 1];
      }
      const float wm = wgt[m] * inv;
      up0 += wm * s0; up1 += wm * s1;
    }
    const int d = lane * 4;
    const float4 xv  = *reinterpret_cast<const float4*>(&x[(size_t)(r0 + rowb) * XROW + d]);
    const float4 w00 = *reinterpret_cast<const float4*>(&Wout[d]);
    const float4 w10 = *reinterpret_cast<const float4*>(&Wout[512 + d]);
    float o0 = xv.x * w00.x + xv.y * w00.y + xv.z * w00.z + xv.w * w00.w;
    float o1 = xv.x * w10.x + xv.y * w10.y + xv.z * w10.z + xv.w * w10.w;
    #pragma unroll
    for (int off = 1; off < 64; off <<= 1) {
      o0 += __shfl_xor(o0, off);
      o1 += __shfl_xor(o1, off);
    }
    if (lane == 0) {
      const int n = (int)blockIdx.x * 8 + g;
      out[n * 2 + 0] = o0 + up0 + bout[0];
      out[n * 2 + 1] = o1 + up1 + bout[1];
    }
  }
}

extern "C" void kernel_launch(void* const* d_in, const int* in_sizes, int n_in,
                              void* d_out, int out_size, void* d_ws, size_t ws_size,
                              hipStream_t stream) {
  const float* x     = (const float*)d_in[0];
  const float* endi  = (const float*)d_in[1];
  // d_in[2] = max_chain (==8, hard-coded)
  const float* Wc    = (const float*)d_in[3];
  const float* bc    = (const float*)d_in[4];
  const float* Wcs   = (const float*)d_in[5];
  const float* Wanti = (const float*)d_in[6];
  const float* Wout  = (const float*)d_in[7];
  const float* bout  = (const float*)d_in[8];
  float* out = (float*)d_out;

  char* ws = (char*)d_ws;
  short* Wt = (short*)ws;                 // 6*256*256*2 = 768 KB (fragment layout)
  float* bq = (float*)(ws + 786432);      // 1 KB

  prep_kernel<<<dim3(256), dim3(256), 0, stream>>>(Wc, bc, Wcs, Wanti, Wt, bq);
  chain_kernel<<<dim3(512), dim3(1024), 0, stream>>>(x, endi, Wt, bq, bc, Wout, bout, out);
}

// Round 23
// 256.221 us; speedup vs baseline: 1.1304x; 1.0677x over previous
//
#include <hip/hip_runtime.h>
#include <hip/hip_bf16.h>

#define FEATN 256
#define XROW  2048      // L*FEAT
#define MT    64        // rows per workgroup
#define NW    16        // waves per workgroup (each owns 16 output cols)
#define LDST  264       // padded LDS row stride (bf16 elems)
#define TILE  (MT * LDST)
#define NSTEP 7

using f32x4 = __attribute__((ext_vector_type(4))) float;
using s16x8 = __attribute__((ext_vector_type(8))) short;

__device__ __forceinline__ short f2bf(float f) {
  __hip_bfloat16 h = __float2bfloat16(f);     // RTNE; pairs compile to v_cvt_pk_bf16_f32
  return *reinterpret_cast<short*>(&h);
}

__device__ __forceinline__ f32x4 ntload4(const float* p) {
  return __builtin_nontemporal_load(reinterpret_cast<const f32x4*>(p));
}

__device__ __forceinline__ s16x8 pack8(const f32x4 a, const f32x4 b) {
  s16x8 r;
  r[0] = f2bf(a[0]); r[1] = f2bf(a[1]); r[2] = f2bf(a[2]); r[3] = f2bf(a[3]);
  r[4] = f2bf(b[0]); r[5] = f2bf(b[1]); r[6] = f2bf(b[2]); r[7] = f2bf(b[3]);
  return r;
}

// 16-lane butterfly reduce via DPP (VALU-only; no LDS-pipe traffic).
__device__ __forceinline__ float dpp_red16(float x) {
  x += __int_as_float(__builtin_amdgcn_update_dpp(0, __float_as_int(x), 0xB1, 0xF, 0xF, true));  // xor 1
  x += __int_as_float(__builtin_amdgcn_update_dpp(0, __float_as_int(x), 0x4E, 0xF, 0xF, true));  // xor 2
  x += __int_as_float(__builtin_amdgcn_update_dpp(0, __float_as_int(x), 0x141, 0xF, 0xF, true)); // xor 4
  x += __int_as_float(__builtin_amdgcn_update_dpp(0, __float_as_int(x), 0x140, 0xF, 0xF, true)); // xor 8
  return x;
}

// ---------------- weight prep ----------------
// Emits MFMA-B-fragment-layout bf16 weights:
//   flat: b*65536 + (n>>4)*4096 + (k>>5)*512 + (((k>>3)&3)*16 + (n&15))*8 + (k&7)
// 0: Wq = Wcs@Wc1   1: Wqc = Wcs@Wc2   2: Wc1   3: Wc2   4: Anti1   5: Anti2
__global__ void prep_kernel(const float* __restrict__ Wc, const float* __restrict__ bc,
                            const float* __restrict__ Wcs, const float* __restrict__ Wanti,
                            short* __restrict__ Wt, float* __restrict__ bq) {
  __shared__ float wrow[FEATN];
  __shared__ float red[FEATN];
  const int n = blockIdx.x, k = threadIdx.x;
  wrow[k] = Wcs[n * FEATN + k];
  __syncthreads();
  float a0 = 0.f, a1 = 0.f;
  #pragma unroll 8
  for (int j = 0; j < FEATN; ++j) {
    const float w = wrow[j];
    a0 += w * Wc[j * 512 + k];
    a1 += w * Wc[j * 512 + 256 + k];
  }
  red[k] = wrow[k] * bc[k];
  __syncthreads();
  for (int off = 128; off > 0; off >>= 1) {
    if (k < off) red[k] += red[k + off];
    __syncthreads();
  }
  if (k == 0) bq[n] = red[0];
  const int fo = (n >> 4) * 4096 + (k >> 5) * 512 + (((k >> 3) & 3) * 16 + (n & 15)) * 8 + (k & 7);
  Wt[0 * 65536 + fo] = f2bf(a0);
  Wt[1 * 65536 + fo] = f2bf(a1);
  Wt[2 * 65536 + fo] = f2bf(Wc[n * 512 + k]);
  Wt[3 * 65536 + fo] = f2bf(Wc[n * 512 + 256 + k]);
  Wt[4 * 65536 + fo] = f2bf(Wanti[n * 512 + k]);
  Wt[5 * 65536 + fo] = f2bf(Wanti[n * 512 + 256 + k]);
}

// ---------------- fused recurrence + output kernel ----------------
// R19 (best: 257us) restored verbatim, with redP/selP padded (+1 col) to
// break the 32-way cs-gather and 4-way selP-write bank conflicts.
__global__ __launch_bounds__(1024, 4)
void chain_kernel(const float* __restrict__ x, const float* __restrict__ endi,
                  const short* __restrict__ Wt, const float* __restrict__ bq,
                  const float* __restrict__ bc, const float* __restrict__ Wout,
                  const float* __restrict__ bout, float* __restrict__ out) {
  __shared__ short sbuf[2 * TILE];               // 67584 B ping-pong bf16 tiles
  __shared__ float redP[MT][NW + 1];             // 4352 B (padded)
  __shared__ float selP[MT][2 * NW + 1];         // 8448 B (padded)
  __shared__ float cpL[MT], cumL[MT], seL[MT], csL[MT], eiL[MT];   // 1280 B

  const int tid  = (int)threadIdx.x;
  const int lane = tid & 63;
  const int wave = tid >> 6;                     // 0..15
  const int lr   = lane & 15;
  const int lh   = lane >> 4;
  const int r0   = (int)blockIdx.x * MT;

  if (tid < MT) { cpL[tid] = 1.f; cumL[tid] = 0.f; seL[tid] = 0.f; }
  for (int i = tid; i < MT * (2 * NW + 1); i += 1024) (&selP[0][0])[i] = 0.f;

  // stage x0 into both slots (s0 == x_t at t=0): 8 bf16/thread, 2 iters, b128
  #pragma unroll
  for (int i = 0; i < 2; ++i) {
    const int f = i * 8192 + tid * 8;
    const int row = f >> 8, col = f & 255;
    const float* src = &x[(size_t)(r0 + row) * XROW + col];
    const s16x8 b = pack8(ntload4(src), ntload4(src + 4));
    *reinterpret_cast<s16x8*>(&sbuf[row * LDST + col]) = b;
    *reinterpret_cast<s16x8*>(&sbuf[TILE + row * LDST + col]) = b;
  }

  const int wcol = wave * 16 + lr;               // this wave's output col
  const short* wfb = Wt + wave * 4096 + lane * 8;   // fragment-layout base
  const int abase = lr * LDST + lh * 8;
  const float bqv = bq[wcol];
  const float bcv = bc[wcol];
  const float wo0 = Wout[256 + wcol];
  const float wo1 = Wout[768 + wcol];
  const f32x4 fzero = {0.f, 0.f, 0.f, 0.f};

  // s state in registers: sreg[m][e] = s[row = m*16+lh*4+e][col = wcol]
  float sreg[4][4];
  #pragma unroll
  for (int m = 0; m < 4; ++m)
    #pragma unroll
    for (int e = 0; e < 4; ++e)
      sreg[m][e] = x[(size_t)(r0 + m * 16 + lh * 4 + e) * XROW + wcol];

  __syncthreads();

  for (int t = 0; t < NSTEP; ++t) {
    const int so = (t & 1) * TILE;               // holds s_t (then x_{t+1})
    const int xo = ((t + 1) & 1) * TILE;         // holds x_t (then s_{t+1})

    // ---- sweep1 (fused): AccA = s@WqT + xt@WqcT ; AccB = s@Wc1T ;
    //      AccN = xt@Anti1T   (each a-frag read once) ----
    f32x4 AccA[4], AccB[4], AccN[4];
    #pragma unroll
    for (int m = 0; m < 4; ++m) { AccA[m] = fzero; AccB[m] = fzero; AccN[m] = fzero; }

    #pragma unroll 1
    for (int ks = 0; ks < 8; ++ks) {
      const short* p = wfb + ks * 512;
      {   // sub-phase A: s-operand matrices
        const s16x8 b0 = *reinterpret_cast<const s16x8*>(p + 0 * 65536);
        const s16x8 b2 = *reinterpret_cast<const s16x8*>(p + 2 * 65536);
        #pragma unroll
        for (int m = 0; m < 4; ++m) {
          const s16x8 a_s = *reinterpret_cast<const s16x8*>(&sbuf[so + abase + m * (16 * LDST) + ks * 32]);
          AccA[m] = __builtin_amdgcn_mfma_f32_16x16x32_bf16(a_s, b0, AccA[m], 0, 0, 0);
          AccB[m] = __builtin_amdgcn_mfma_f32_16x16x32_bf16(a_s, b2, AccB[m], 0, 0, 0);
        }
      }
      {   // sub-phase B: x_t-operand matrices
        const s16x8 b1 = *reinterpret_cast<const s16x8*>(p + 1 * 65536);
        const s16x8 b4 = *reinterpret_cast<const s16x8*>(p + 4 * 65536);
        #pragma unroll
        for (int m = 0; m < 4; ++m) {
          const s16x8 a_x = *reinterpret_cast<const s16x8*>(&sbuf[xo + abase + m * (16 * LDST) + ks * 32]);
          AccA[m] = __builtin_amdgcn_mfma_f32_16x16x32_bf16(a_x, b1, AccA[m], 0, 0, 0);
          AccN[m] = __builtin_amdgcn_mfma_f32_16x16x32_bf16(a_x, b4, AccN[m], 0, 0, 0);
        }
      }
    }
    __syncthreads();   // B1: all s-slot AND x_t-slot reads done

    // ---- stage x_{t+1} into the s-slot (transient b128) ----
    #pragma unroll
    for (int i = 0; i < 2; ++i) {
      const int f = i * 8192 + tid * 8;
      const int row = f >> 8, col = f & 255;
      const float* src = &x[(size_t)(r0 + row) * XROW + (t + 1) * FEATN + col];
      const s16x8 b = pack8(ntload4(src), ntload4(src + 4));
      *reinterpret_cast<s16x8*>(&sbuf[so + row * LDST + col]) = b;
    }
    __syncthreads();   // B2: x_{t+1} visible

    // ---- sweep2 (fused): AccB += x_{t+1}@Wc2T ; AccN += x_{t+1}@Anti2T ----
    #pragma unroll 1
    for (int ks = 0; ks < 8; ++ks) {
      const short* p = wfb + ks * 512;
      const s16x8 b3 = *reinterpret_cast<const s16x8*>(p + 3 * 65536);
      const s16x8 b5 = *reinterpret_cast<const s16x8*>(p + 5 * 65536);
      #pragma unroll
      for (int m = 0; m < 4; ++m) {
        const s16x8 a_n = *reinterpret_cast<const s16x8*>(&sbuf[so + abase + m * (16 * LDST) + ks * 32]);
        AccB[m] = __builtin_amdgcn_mfma_f32_16x16x32_bf16(a_n, b3, AccB[m], 0, 0, 0);
        AccN[m] = __builtin_amdgcn_mfma_f32_16x16x32_bf16(a_n, b5, AccN[m], 0, 0, 0);
      }
    }

    // ---- dot: sum_d (AccA+bq)*(AccB+bc) via DPP butterfly ----
    #pragma unroll
    for (int m = 0; m < 4; ++m) {
      #pragma unroll
      for (int e = 0; e < 4; ++e) {
        const float p = dpp_red16((AccA[m][e] + bqv) * (AccB[m][e] + bcv));
        if (lr == 0) redP[m * 16 + lh * 4 + e][wave] = p;
      }
    }
    __syncthreads();   // B3: redP visible

    // cs/cumprod bookkeeping (tid<64)
    if (tid < MT) {
      float d = 0.f;
      #pragma unroll
      for (int w = 0; w < NW; ++w) d += redP[tid][w];
      const float cs = 1.f / (1.f + __expf(-d));
      const float cp = cpL[tid] * cs;
      cpL[tid] = cp;
      const float ei = endi[(size_t)(r0 + tid) * 8 + (t + 1)];
      cumL[tid] += cp * ei;
      seL[tid] += ei;
      csL[tid] = cs;
      eiL[tid] = ei;
    }
    __syncthreads();   // B4: csL/eiL visible

    // ---- update: s += tanh(cs*AccN); selP projection; s_{t+1} -> x_t slot ----
    #pragma unroll
    for (int m = 0; m < 4; ++m) {
      #pragma unroll
      for (int e = 0; e < 4; ++e) {
        const int row = m * 16 + lh * 4 + e;
        const float cs = csL[row];
        const float ag = cs * AccN[m][e];
        const float ex = __expf(2.f * ag);
        const float th = 1.f - 2.f / (ex + 1.f);
        const float sn = sreg[m][e] + th;
        sreg[m][e] = sn;
        sbuf[xo + row * LDST + wcol] = f2bf(sn);
        if (eiL[row] != 0.f) {                   // uniform across the lr group
          const float p0 = dpp_red16(sn * wo0);
          const float p1 = dpp_red16(sn * wo1);
          if (lr == 0) { selP[row][wave * 2] = p0; selP[row][wave * 2 + 1] = p1; }
        }
      }
    }
    __syncthreads();   // B5: s_{t+1} visible for next sweep1
  }

  // final: one group of 8 rows per wave (waves 0..7), softmax over cum, combine
  if (wave < 8) {
    const int g = wave;
    const int rowb = g * 8;
    float c[8];
    float mx = -3.4e38f;
    #pragma unroll
    for (int m = 0; m < 8; ++m) {
      c[m] = cumL[rowb + m] - (1.f - seL[rowb + m]) * 10000.f;
      mx = fmaxf(mx, c[m]);
    }
    float sum = 0.f;
    float wgt[8];
    #pragma unroll
    for (int m = 0; m < 8; ++m) { wgt[m] = __expf(c[m] - mx); sum += wgt[m]; }
    const float inv = 1.f / sum;
    float up0 = 0.f, up1 = 0.f;
    #pragma unroll
    for (int m = 0; m < 8; ++m) {
      float s0 = 0.f, s1 = 0.f;
      #pragma unroll
      for (int w = 0; w < NW; ++w) {
        s0 += selP[rowb + m][w * 2];
        s1 += selP[rowb + m][w * 2 + 1];
      }
      const float wm = wgt[m] * inv;
      up0 += wm * s0; up1 += wm * s1;
    }
    const int d = lane * 4;
    const float4 xv  = *reinterpret_cast<const float4*>(&x[(size_t)(r0 + rowb) * XROW + d]);
    const float4 w00 = *reinterpret_cast<const float4*>(&Wout[d]);
    const float4 w10 = *reinterpret_cast<const float4*>(&Wout[512 + d]);
    float o0 = xv.x * w00.x + xv.y * w00.y + xv.z * w00.z + xv.w * w00.w;
    float o1 = xv.x * w10.x + xv.y * w10.y + xv.z * w10.z + xv.w * w10.w;
    #pragma unroll
    for (int off = 1; off < 64; off <<= 1) {
      o0 += __shfl_xor(o0, off);
      o1 += __shfl_xor(o1, off);
    }
    if (lane == 0) {
      const int n = (int)blockIdx.x * 8 + g;
      out[n * 2 + 0] = o0 + up0 + bout[0];
      out[n * 2 + 1] = o1 + up1 + bout[1];
    }
  }
}

extern "C" void kernel_launch(void* const* d_in, const int* in_sizes, int n_in,
                              void* d_out, int out_size, void* d_ws, size_t ws_size,
                              hipStream_t stream) {
  const float* x     = (const float*)d_in[0];
  const float* endi  = (const float*)d_in[1];
  // d_in[2] = max_chain (==8, hard-coded)
  const float* Wc    = (const float*)d_in[3];
  const float* bc    = (const float*)d_in[4];
  const float* Wcs   = (const float*)d_in[5];
  const float* Wanti = (const float*)d_in[6];
  const float* Wout  = (const float*)d_in[7];
  const float* bout  = (const float*)d_in[8];
  float* out = (float*)d_out;

  char* ws = (char*)d_ws;
  short* Wt = (short*)ws;                 // 6*256*256*2 = 768 KB (fragment layout)
  float* bq = (float*)(ws + 786432);      // 1 KB

  prep_kernel<<<dim3(256), dim3(256), 0, stream>>>(Wc, bc, Wcs, Wanti, Wt, bq);
  chain_kernel<<<dim3(512), dim3(1024), 0, stream>>>(x, endi, Wt, bq, bc, Wout, bout, out);
}